// Round 1
// 460.165 us; speedup vs baseline: 1.0057x; 1.0057x over previous
//
#include <hip/hip_runtime.h>
#include <math.h>

#define ALPHA 0.3f
#define K_NB  32
#define C_DIM 64
#define H_DIM 64
#define WPB   8   // waves per block (512 threads); 10000/8 = 1250 blocks exactly

__device__ __forceinline__ float leaky(float x) { return x >= 0.0f ? x : ALPHA * x; }

__device__ __forceinline__ float lane_bcast(float v, int l) {
    return __uint_as_float(__builtin_amdgcn_readlane(__float_as_uint(v), l));
}

// Stage 1: hq[n][h] = leaky_relu(embs[n] @ Qw + Qb), one wave per node, lane = h.
__global__ void __launch_bounds__(WPB * 64) stage1_kernel(
        const float* __restrict__ embs, const float* __restrict__ Qw,
        const float* __restrict__ Qb, float* __restrict__ hq, int N) {
    __shared__ float s_Qw[C_DIM * H_DIM];          // 16 KB
    int tid  = threadIdx.x;
    int wave = tid >> 6, lane = tid & 63;
    int n = blockIdx.x * WPB + wave;
    bool valid = (n < N);
    int nsafe = valid ? n : 0;

    // Prefetch own operands BEFORE the LDS staging loop so their global
    // latency hides under the fill + barrier instead of following it.
    float e  = embs[(size_t)nsafe * C_DIM + lane];
    float qb = Qb[lane];

    const float4* q4 = (const float4*)Qw;
    float4* s4 = (float4*)s_Qw;
    #pragma unroll
    for (int i = 0; i < (C_DIM * H_DIM / 4) / (WPB * 64); ++i)
        s4[tid + i * WPB * 64] = q4[tid + i * WPB * 64];
    __syncthreads();
    if (!valid) return;

    float a0 = qb, a1 = 0.0f;
    #pragma unroll
    for (int c = 0; c < C_DIM; c += 2) {
        float w0 = s_Qw[c * H_DIM + lane];         // adjacent pair -> ds_read2_b32
        float w1 = s_Qw[(c + 1) * H_DIM + lane];
        a0 = fmaf(lane_bcast(e, c),     w0, a0);
        a1 = fmaf(lane_bcast(e, c + 1), w1, a1);
    }
    hq[(size_t)n * H_DIM + lane] = leaky(a0 + a1);
}

// Stage 2: weighted neighbor-average of hq, concat with embs, 128->64 linear,
// leaky_relu, L2 normalize. One wave per node, lane = h.
__global__ void __launch_bounds__(WPB * 64) stage2_kernel(
        const float* __restrict__ embs, const float* __restrict__ weights,
        const int*   __restrict__ nbset, const float* __restrict__ Ww,
        const float* __restrict__ Wb, const float* __restrict__ hq,
        float* __restrict__ out, int N) {
    __shared__ float s_Ww[(C_DIM + H_DIM) * H_DIM];   // 32 KB
    int tid  = threadIdx.x;
    int wave = tid >> 6, lane = tid & 63;
    int n = blockIdx.x * WPB + wave;
    bool valid = (n < N);
    int nsafe = valid ? n : 0;

    // Issue the long-latency globals first: nbset row (coalesced 128 B),
    // then the DEPENDENT random weights gather (the slowest op in the whole
    // kernel: 32 cold HBM lines), plus embs row and bias. All of this flies
    // while the 32 KB Ww staging + barrier runs.
    const int* nb_row = nbset + (size_t)nsafe * K_NB;
    int   nb_l = nb_row[lane & (K_NB - 1)];
    float e    = embs[(size_t)nsafe * C_DIM + lane];
    float wb   = Wb[lane];
    float w_l  = weights[(size_t)nsafe * (size_t)N + nb_l];

    const float4* w4 = (const float4*)Ww;
    float4* s4 = (float4*)s_Ww;
    #pragma unroll
    for (int i = 0; i < ((C_DIM + H_DIM) * H_DIM / 4) / (WPB * 64); ++i)
        s4[tid + i * WPB * 64] = w4[tid + i * WPB * 64];
    __syncthreads();
    if (!valid) return;

    // Σw via 5-step butterfly: lanes 32..63 mirror 0..31, so a 32-wide
    // xor-reduce over the full wave yields the 32-neighbor sum in all lanes.
    float sw = w_l;
    #pragma unroll
    for (int off = 1; off <= 16; off <<= 1) sw += __shfl_xor(sw, off, 64);

    float acc = 0.0f;
    #pragma unroll
    for (int k = 0; k < K_NB; ++k) {
        int   nb = __builtin_amdgcn_readlane(nb_l, k);     // uniform SGPR base
        float w  = lane_bcast(w_l, k);                     // broadcast from vector reg
        acc = fmaf(w, hq[(size_t)nb * H_DIM + lane], acc); // coalesced 256 B row
    }
    float ws = acc / (sw + 1e-6f);

    float o0 = wb, o1 = 0.0f;
    #pragma unroll
    for (int c = 0; c < C_DIM; c += 2) {
        float m0 = s_Ww[c * H_DIM + lane];
        float m1 = s_Ww[(c + 1) * H_DIM + lane];
        o0 = fmaf(lane_bcast(e, c),     m0, o0);
        o1 = fmaf(lane_bcast(e, c + 1), m1, o1);
    }
    #pragma unroll
    for (int c = 0; c < C_DIM; c += 2) {
        float m0 = s_Ww[(C_DIM + c) * H_DIM + lane];
        float m1 = s_Ww[(C_DIM + c + 1) * H_DIM + lane];
        o0 = fmaf(lane_bcast(ws, c),     m0, o0);
        o1 = fmaf(lane_bcast(ws, c + 1), m1, o1);
    }
    float o = leaky(o0 + o1);

    float sq = o * o;
    #pragma unroll
    for (int off = 32; off > 0; off >>= 1) sq += __shfl_xor(sq, off, 64);
    out[(size_t)n * H_DIM + lane] = o / (sqrtf(sq) + 1e-6f);
}

extern "C" void kernel_launch(void* const* d_in, const int* in_sizes, int n_in,
                              void* d_out, int out_size, void* d_ws, size_t ws_size,
                              hipStream_t stream) {
    const float* embs    = (const float*)d_in[0];   // (1, N, 64)
    const float* weights = (const float*)d_in[1];   // (N, N)
    const int*   nbset   = (const int*)  d_in[2];   // (N, 32)
    const float* Qw      = (const float*)d_in[3];   // (64, 64)
    const float* Qb      = (const float*)d_in[4];   // (64,)
    const float* Ww      = (const float*)d_in[5];   // (128, 64)
    const float* Wb      = (const float*)d_in[6];   // (64,)
    float* out = (float*)d_out;                     // (1, N, 64)

    const int N = in_sizes[2] / K_NB;               // 10000
    float* hq = (float*)d_ws;                       // N*64 floats = 2.56 MB

    int blocks = (N + WPB - 1) / WPB;
    stage1_kernel<<<blocks, WPB * 64, 0, stream>>>(embs, Qw, Qb, hq, N);
    stage2_kernel<<<blocks, WPB * 64, 0, stream>>>(embs, weights, nbset,
                                                   Ww, Wb, hq, out, N);
}